// Round 1
// baseline (696.337 us; speedup 1.0000x reference)
//
#include <hip/hip_runtime.h>

// Problem constants (fixed by reference)
#define DB 8
#define DT 4096
#define DC 1024
#define GM (DB*DT)   // 32768
#define GN (2*DC)    // 2048 (state cols 0..1023, gate cols 1024..2047)
#define GK DC        // 1024

typedef _Float16 f16;
typedef _Float16 f16x8 __attribute__((ext_vector_type(8)));
typedef _Float16 f16x4 __attribute__((ext_vector_type(4)));
typedef float    f32x4 __attribute__((ext_vector_type(4)));

__device__ __forceinline__ void async_copy16(const void* g, void* l) {
    __builtin_amdgcn_global_load_lds((const __attribute__((address_space(1))) void*)g,
                                     (__attribute__((address_space(3))) void*)l,
                                     16, 0, 0);
}

// ---- fp32 -> f16 conversion of x -------------------------------------------
__global__ __launch_bounds__(256) void conv_x_kernel(const float* __restrict__ x,
                                                     f16* __restrict__ xh) {
    const size_t i = (size_t)blockIdx.x * 256 + threadIdx.x; // 8,388,608 threads
    const f32x4 v = *(const f32x4*)(x + 4*i);
    f16x4 h; h.x = (f16)v.x; h.y = (f16)v.y; h.z = (f16)v.z; h.w = (f16)v.w;
    *(f16x4*)(xh + 4*i) = h;
}

// ---- fp32 -> f16 of [W_state; W_gate] as one [2048,1024] row-major matrix --
__global__ __launch_bounds__(256) void conv_w_kernel(const float* __restrict__ Ws,
                                                     const float* __restrict__ Wg,
                                                     f16* __restrict__ wc) {
    const int i = blockIdx.x * 256 + threadIdx.x;  // 524,288 threads
    const int e = i * 4;
    const int n = e >> 10;
    const int k = e & 1023;
    const float* src = (n < DC) ? (Ws + (size_t)n * DC + k)
                                : (Wg + (size_t)(n - DC) * DC + k);
    const f32x4 v = *(const f32x4*)src;
    f16x4 h; h.x = (f16)v.x; h.y = (f16)v.y; h.z = (f16)v.z; h.w = (f16)v.w;
    *(f16x4*)(wc + e) = h;
}

// ---- fused GEMM: [32768,1024] x [2048,1024]^T, bias + (sigmoid for gate) ---
// A, B both row-major with K contiguous (NT GEMM). 128x128 tile, BK=64,
// 4 waves, each 64x64 via 4x4 grid of 16x16x32 f16 MFMAs. m97 structure.
__global__ __launch_bounds__(256, 2) void gemm_kernel(
        const f16* __restrict__ xh, const f16* __restrict__ wc,
        const float* __restrict__ b_state, const float* __restrict__ b_gate,
        f16* __restrict__ pxh, float* __restrict__ outg) {
    __shared__ f16 lds_a[128 * 64];   // 16 KiB
    __shared__ f16 lds_b[128 * 64];   // 16 KiB

    const int tid  = threadIdx.x;
    const int lane = tid & 63;
    const int bn   = blockIdx.x & 15;  // 16 n-tiles
    const int bm   = blockIdx.x >> 4;  // 256 m-tiles
    const int wave = tid >> 6;
    const int wm   = (wave & 1) * 64;
    const int wn   = (wave >> 1) * 64;
    const int lr   = lane & 15;        // A-op row / B-op col / D col
    const int lq   = lane >> 4;        // quad

    f32x4 acc[4][4] = {};

    const int kc = tid & 7;            // 16B chunk within a 64-half row
    const int rw = tid >> 3;           // row contribution from tid
    const int ldsbase = (tid & 192) * 16;  // wave-uniform byte base (wave*1024)

    for (int kt = 0; kt < GK / 64; ++kt) {
        const int k0 = kt * 64;
        #pragma unroll
        for (int i = 0; i < 4; ++i) {
            const int row = i * 32 + rw;
            async_copy16(xh + (size_t)(bm * 128 + row) * GK + k0 + kc * 8,
                         (char*)lds_a + ldsbase + i * 4096);
            async_copy16(wc + (size_t)(bn * 128 + row) * GK + k0 + kc * 8,
                         (char*)lds_b + ldsbase + i * 4096);
        }
        __syncthreads();   // drains vmcnt before barrier (m97 semantics)
        #pragma unroll
        for (int ks = 0; ks < 2; ++ks) {
            f16x8 af[4], bf[4];
            #pragma unroll
            for (int t = 0; t < 4; ++t) {
                af[t] = *(const f16x8*)&lds_a[(wm + t * 16 + lr) * 64 + ks * 32 + lq * 8];
                bf[t] = *(const f16x8*)&lds_b[(wn + t * 16 + lr) * 64 + ks * 32 + lq * 8];
            }
            #pragma unroll
            for (int im = 0; im < 4; ++im)
                #pragma unroll
                for (int in = 0; in < 4; ++in)
                    acc[im][in] = __builtin_amdgcn_mfma_f32_16x16x32_f16(
                        af[im], bf[in], acc[im][in], 0, 0, 0);
        }
        __syncthreads();
    }

    // Epilogue. D layout: col = lane&15, row = quad*4 + reg (verified m89).
    const int gm0 = bm * 128 + wm + lq * 4;
    const int gn0 = bn * 128 + wn + lr;
    if (bn < 8) {
        // state projection: px = acc + b_state, store f16
        #pragma unroll
        for (int in = 0; in < 4; ++in) {
            const int gn = gn0 + in * 16;
            const float bias = b_state[gn];
            #pragma unroll
            for (int im = 0; im < 4; ++im) {
                const int gm = gm0 + im * 16;
                #pragma unroll
                for (int r = 0; r < 4; ++r)
                    pxh[(size_t)(gm + r) * DC + gn] = (f16)(acc[im][in][r] + bias);
            }
        }
    } else {
        // gate: g = sigmoid(acc + b_gate), store fp32 into d_out (scan reuses)
        #pragma unroll
        for (int in = 0; in < 4; ++in) {
            const int gn   = gn0 + in * 16;
            const int gcol = gn - DC;
            const float bias = b_gate[gcol];
            #pragma unroll
            for (int im = 0; im < 4; ++im) {
                const int gm = gm0 + im * 16;
                #pragma unroll
                for (int r = 0; r < 4; ++r) {
                    const float v = acc[im][in][r] + bias;
                    outg[(size_t)(gm + r) * DC + gcol] = 1.0f / (1.0f + __expf(-v));
                }
            }
        }
    }
}

// ---- sequential scan over T: s = tanh(p_t + s); out = g_t * s --------------
// 8192 independent (b,c) chains; latency-bound. tanh(z) = 1 - 2/(1+2^(L*z)),
// L = 2*log2(e); track sL = L*s so chain is add->exp2->add->rcp->fma.
__global__ __launch_bounds__(64, 1) void scan_kernel(const f16* __restrict__ pxh,
                                                     float* __restrict__ out) {
    const int tid = blockIdx.x * 64 + threadIdx.x;  // 0..8191
    const int b = tid >> 10, c = tid & 1023;
    const size_t base = (size_t)b * DT * DC + c;
    const float L = 2.8853900817779268f;  // 2*log2(e)

    constexpr int U = 32;
    float pA[U], gA[U], pB[U], gB[U];
    #pragma unroll
    for (int i = 0; i < U; ++i) {
        const size_t idx = base + (size_t)i * DC;
        pA[i] = (float)pxh[idx] * L;
        gA[i] = out[idx];                // g (sigmoid) was staged here by gemm
    }

    float sL = 0.0f, s = 0.0f;
    const int NCH = DT / U;  // 128
    for (int ch = 0; ch < NCH; ++ch) {
        if (ch + 1 < NCH) {
            const size_t nb = base + (size_t)(ch + 1) * U * DC;
            #pragma unroll
            for (int i = 0; i < U; ++i) {
                pB[i] = (float)pxh[nb + (size_t)i * DC] * L;
                gB[i] = out[nb + (size_t)i * DC];
            }
        }
        const size_t cb = base + (size_t)ch * U * DC;
        #pragma unroll
        for (int i = 0; i < U; ++i) {
            const float u = pA[i] + sL;                       // L*(p_t + s)
            const float e = __builtin_amdgcn_exp2f(u);
            const float r = __builtin_amdgcn_rcpf(e + 1.0f);  // 1/(1+e^{2z})
            s  = fmaf(-2.0f, r, 1.0f);                        // tanh
            sL = fmaf(-2.0f * L, r, L);                       // L*tanh
            out[cb + (size_t)i * DC] = gA[i] * s;             // g * s (off chain)
        }
        #pragma unroll
        for (int i = 0; i < U; ++i) { pA[i] = pB[i]; gA[i] = gB[i]; }
    }
    out[(size_t)DB * DT * DC + tid] = s;  // final_state [B,C]
}

extern "C" void kernel_launch(void* const* d_in, const int* in_sizes, int n_in,
                              void* d_out, int out_size, void* d_ws, size_t ws_size,
                              hipStream_t stream) {
    const float* x  = (const float*)d_in[0];
    const float* Ws = (const float*)d_in[1];
    const float* bs = (const float*)d_in[2];
    const float* Wg = (const float*)d_in[3];
    const float* bg = (const float*)d_in[4];
    float* out = (float*)d_out;

    // workspace layout (needs 138,412,032 B):
    //   xh  : f16[32768*1024]  @ 0          (64 MiB)
    //   wc  : f16[2048*1024]   @ 64 MiB     ( 4 MiB)
    //   pxh : f16[32768*1024]  @ 68 MiB     (64 MiB)
    char* ws = (char*)d_ws;
    f16* xh  = (f16*)ws;
    f16* wc  = (f16*)(ws + (size_t)67108864);
    f16* pxh = (f16*)(ws + (size_t)67108864 + 4194304);

    hipLaunchKernelGGL(conv_x_kernel, dim3(32768), dim3(256), 0, stream, x, xh);
    hipLaunchKernelGGL(conv_w_kernel, dim3(2048), dim3(256), 0, stream, Ws, Wg, wc);
    hipLaunchKernelGGL(gemm_kernel, dim3(4096), dim3(256), 0, stream,
                       xh, wc, bs, bg, pxh, out);
    hipLaunchKernelGGL(scan_kernel, dim3(128), dim3(64), 0, stream, pxh, out);
}

// Round 2
// 451.699 us; speedup vs baseline: 1.5416x; 1.5416x over previous
//
#include <hip/hip_runtime.h>

// Problem constants (fixed by reference)
#define DB 8
#define DT 4096
#define DC 1024
#define GM (DB*DT)   // 32768
#define GN (2*DC)    // 2048 (state cols 0..1023, gate cols 1024..2047)
#define GK DC        // 1024

// Segmented-scan parameters
#define SEG 128      // segment length (outputs per worker)
#define NSEG (DT/SEG)
#define WU 64        // warmup steps (contraction kills s0 error: ~e^-38 typ)
#define UCH 16       // prefetch chunk

typedef _Float16 f16;
typedef _Float16 f16x8 __attribute__((ext_vector_type(8)));
typedef _Float16 f16x4 __attribute__((ext_vector_type(4)));
typedef float    f32x4 __attribute__((ext_vector_type(4)));

__device__ __forceinline__ void async_copy16(const void* g, void* l) {
    __builtin_amdgcn_global_load_lds((const __attribute__((address_space(1))) void*)g,
                                     (__attribute__((address_space(3))) void*)l,
                                     16, 0, 0);
}

// ---- fp32 -> f16 conversion of x -------------------------------------------
__global__ __launch_bounds__(256) void conv_x_kernel(const float* __restrict__ x,
                                                     f16* __restrict__ xh) {
    const size_t i = (size_t)blockIdx.x * 256 + threadIdx.x;
    const f32x4 v = *(const f32x4*)(x + 4*i);
    f16x4 h; h.x = (f16)v.x; h.y = (f16)v.y; h.z = (f16)v.z; h.w = (f16)v.w;
    *(f16x4*)(xh + 4*i) = h;
}

// ---- fp32 -> f16 of [W_state; W_gate] as one [2048,1024] row-major matrix --
__global__ __launch_bounds__(256) void conv_w_kernel(const float* __restrict__ Ws,
                                                     const float* __restrict__ Wg,
                                                     f16* __restrict__ wc) {
    const int i = blockIdx.x * 256 + threadIdx.x;
    const int e = i * 4;
    const int n = e >> 10;
    const int k = e & 1023;
    const float* src = (n < DC) ? (Ws + (size_t)n * DC + k)
                                : (Wg + (size_t)(n - DC) * DC + k);
    const f32x4 v = *(const f32x4*)src;
    f16x4 h; h.x = (f16)v.x; h.y = (f16)v.y; h.z = (f16)v.z; h.w = (f16)v.w;
    *(f16x4*)(wc + e) = h;
}

// ---- fused GEMM: [32768,1024] x [2048,1024]^T, bias + (sigmoid for gate) ---
// 128x128 tile, BK=64, 4 waves, each 64x64 via 4x4 grid of 16x16x32 f16 MFMAs.
template<bool GF16>
__global__ __launch_bounds__(256, 2) void gemm_kernel(
        const f16* __restrict__ xh, const f16* __restrict__ wc,
        const float* __restrict__ b_state, const float* __restrict__ b_gate,
        f16* __restrict__ pxh, f16* __restrict__ gh, float* __restrict__ outg) {
    __shared__ f16 lds_a[128 * 64];
    __shared__ f16 lds_b[128 * 64];

    const int tid  = threadIdx.x;
    const int lane = tid & 63;
    const int bn   = blockIdx.x & 15;
    const int bm   = blockIdx.x >> 4;
    const int wave = tid >> 6;
    const int wm   = (wave & 1) * 64;
    const int wn   = (wave >> 1) * 64;
    const int lr   = lane & 15;
    const int lq   = lane >> 4;

    f32x4 acc[4][4] = {};

    const int kc = tid & 7;
    const int rw = tid >> 3;
    const int ldsbase = (tid & 192) * 16;

    for (int kt = 0; kt < GK / 64; ++kt) {
        const int k0 = kt * 64;
        #pragma unroll
        for (int i = 0; i < 4; ++i) {
            const int row = i * 32 + rw;
            async_copy16(xh + (size_t)(bm * 128 + row) * GK + k0 + kc * 8,
                         (char*)lds_a + ldsbase + i * 4096);
            async_copy16(wc + (size_t)(bn * 128 + row) * GK + k0 + kc * 8,
                         (char*)lds_b + ldsbase + i * 4096);
        }
        __syncthreads();
        #pragma unroll
        for (int ks = 0; ks < 2; ++ks) {
            f16x8 af[4], bf[4];
            #pragma unroll
            for (int t = 0; t < 4; ++t) {
                af[t] = *(const f16x8*)&lds_a[(wm + t * 16 + lr) * 64 + ks * 32 + lq * 8];
                bf[t] = *(const f16x8*)&lds_b[(wn + t * 16 + lr) * 64 + ks * 32 + lq * 8];
            }
            #pragma unroll
            for (int im = 0; im < 4; ++im)
                #pragma unroll
                for (int in = 0; in < 4; ++in)
                    acc[im][in] = __builtin_amdgcn_mfma_f32_16x16x32_f16(
                        af[im], bf[in], acc[im][in], 0, 0, 0);
        }
        __syncthreads();
    }

    // Epilogue. D layout: col = lane&15, row = quad*4 + reg (verified m89).
    const int gm0 = bm * 128 + wm + lq * 4;
    const int gn0 = bn * 128 + wn + lr;
    if (bn < 8) {
        #pragma unroll
        for (int in = 0; in < 4; ++in) {
            const int gn = gn0 + in * 16;
            const float bias = b_state[gn];
            #pragma unroll
            for (int im = 0; im < 4; ++im) {
                const int gm = gm0 + im * 16;
                #pragma unroll
                for (int r = 0; r < 4; ++r)
                    pxh[(size_t)(gm + r) * DC + gn] = (f16)(acc[im][in][r] + bias);
            }
        }
    } else {
        #pragma unroll
        for (int in = 0; in < 4; ++in) {
            const int gn   = gn0 + in * 16;
            const int gcol = gn - DC;
            const float bias = b_gate[gcol];
            #pragma unroll
            for (int im = 0; im < 4; ++im) {
                const int gm = gm0 + im * 16;
                #pragma unroll
                for (int r = 0; r < 4; ++r) {
                    const float v = acc[im][in][r] + bias;
                    const float sg = 1.0f / (1.0f + __expf(-v));
                    if (GF16) gh[(size_t)(gm + r) * DC + gcol] = (f16)sg;
                    else      outg[(size_t)(gm + r) * DC + gcol] = sg;
                }
            }
        }
    }
}

// ---- segmented scan over T: s = tanh(p_t + s); out = g_t * s ---------------
// 8192 chains x 32 segments of 128 steps; each segment (except first) warms
// up 64 steps from s=0. tanh(z) = 1 - 2/(1+2^(L*z)), L = 2*log2(e); track
// sL = L*s so the dependent chain is fma->exp2->add->rcp->fma.
template<bool GF16>
__global__ __launch_bounds__(256, 4) void scan_kernel(
        const f16* __restrict__ ph, const f16* __restrict__ gh,
        float* __restrict__ out) {
    const int tau   = blockIdx.x * 256 + threadIdx.x;   // 0..262143
    const int seg   = tau >> 13;                        // 0..31 (wave-uniform)
    const int chain = tau & 8191;
    const size_t base = (size_t)(chain >> 10) * ((size_t)DT * DC) + (chain & 1023);
    const float L = 2.8853900817779268f;                // 2*log2(e)
    float sL = 0.0f, s = 0.0f;
    const int t0 = seg * SEG;

    if (seg) {  // warmup: p only, no g, no stores
        const int tw = t0 - WU;
        f16 wA[UCH], wB[UCH];
        #pragma unroll
        for (int i = 0; i < UCH; ++i) wA[i] = ph[base + (size_t)(tw + i) * DC];
        #pragma unroll 1
        for (int ch = 0; ch < WU / UCH; ++ch) {
            #pragma unroll
            for (int i = 0; i < UCH; ++i)   // last iter reads t0..t0+15: valid
                wB[i] = ph[base + (size_t)(tw + (ch + 1) * UCH + i) * DC];
            #pragma unroll
            for (int i = 0; i < UCH; ++i) {
                const float u = fmaf((float)wA[i], L, sL);
                const float e = __builtin_amdgcn_exp2f(u);
                const float r = __builtin_amdgcn_rcpf(e + 1.0f);
                sL = fmaf(-2.0f * L, r, L);
            }
            #pragma unroll
            for (int i = 0; i < UCH; ++i) wA[i] = wB[i];
        }
    }

    float pA[UCH], pB[UCH], gA[UCH], gB[UCH];
    #pragma unroll
    for (int i = 0; i < UCH; ++i) {
        const size_t idx = base + (size_t)(t0 + i) * DC;
        pA[i] = (float)ph[idx] * L;
        gA[i] = GF16 ? (float)gh[idx] : out[idx];
    }
    #pragma unroll 1
    for (int ch = 0; ch < SEG / UCH; ++ch) {
        // GF16: unconditional prefetch (pxh/gh padded by 16 steps for seg 31).
        // fallback: g lives in d_out -> never prefetch into the next segment
        // (its worker is concurrently overwriting g there).
        if (GF16 || (ch + 1 < SEG / UCH)) {
            #pragma unroll
            for (int i = 0; i < UCH; ++i) {
                const size_t idx = base + (size_t)(t0 + (ch + 1) * UCH + i) * DC;
                pB[i] = (float)ph[idx] * L;
                gB[i] = GF16 ? (float)gh[idx] : out[idx];
            }
        }
        #pragma unroll
        for (int i = 0; i < UCH; ++i) {
            const float u = pA[i] + sL;
            const float e = __builtin_amdgcn_exp2f(u);
            const float r = __builtin_amdgcn_rcpf(e + 1.0f);
            s  = fmaf(-2.0f, r, 1.0f);
            sL = fmaf(-2.0f * L, r, L);
            out[base + (size_t)(t0 + ch * UCH + i) * DC] = gA[i] * s;
        }
        #pragma unroll
        for (int i = 0; i < UCH; ++i) { pA[i] = pB[i]; gA[i] = gB[i]; }
    }
    if (seg == NSEG - 1) out[(size_t)DB * DT * DC + chain] = s;  // final_state
}

extern "C" void kernel_launch(void* const* d_in, const int* in_sizes, int n_in,
                              void* d_out, int out_size, void* d_ws, size_t ws_size,
                              hipStream_t stream) {
    const float* x  = (const float*)d_in[0];
    const float* Ws = (const float*)d_in[1];
    const float* bs = (const float*)d_in[2];
    const float* Wg = (const float*)d_in[3];
    const float* bg = (const float*)d_in[4];
    float* out = (float*)d_out;

    char* ws = (char*)d_ws;
    const size_t SZ_XH  = (size_t)GM * GK * 2;            // 64 MiB
    const size_t SZ_WC  = (size_t)GN * GK * 2;            //  4 MiB
    const size_t SZ_PXH = ((size_t)GM + UCH) * DC * 2;    // 64 MiB + 32 KiB pad
    const size_t NEED_F16 = SZ_XH + SZ_WC + 2 * SZ_PXH;   // ~196 MiB

    f16* xh = (f16*)ws;
    f16* wc = (f16*)(ws + SZ_XH);
    f16* pxh = (f16*)(ws + SZ_XH + SZ_WC);
    const bool gf16 = (ws_size >= NEED_F16);
    f16* gh = gf16 ? (f16*)(ws + SZ_XH + SZ_WC + SZ_PXH) : (f16*)nullptr;

    conv_x_kernel<<<dim3(GM * GK / 1024), dim3(256), 0, stream>>>(x, xh);
    conv_w_kernel<<<dim3(GN * GK / 1024), dim3(256), 0, stream>>>(Ws, Wg, wc);
    if (gf16) {
        gemm_kernel<true><<<dim3(4096), dim3(256), 0, stream>>>(
            xh, wc, bs, bg, pxh, gh, out);
        scan_kernel<true><<<dim3(1024), dim3(256), 0, stream>>>(pxh, gh, out);
    } else {
        gemm_kernel<false><<<dim3(4096), dim3(256), 0, stream>>>(
            xh, wc, bs, bg, pxh, gh, out);
        scan_kernel<false><<<dim3(1024), dim3(256), 0, stream>>>(pxh, gh, out);
    }
}

// Round 3
// 442.255 us; speedup vs baseline: 1.5745x; 1.0214x over previous
//
#include <hip/hip_runtime.h>

// Problem constants (fixed by reference)
#define DB 8
#define DT 4096
#define DC 1024
#define GM (DB*DT)   // 32768
#define GN (2*DC)    // 2048 (state cols 0..1023, gate cols 1024..2047)
#define GK DC        // 1024

// Segmented-scan parameters
#define SEG 64       // segment length (outputs per worker) -> 32 waves/CU
#define NSEG (DT/SEG)
#define WU 64        // warmup steps (contraction ~0.55/step kills s0 error)
#define UCH 8        // prefetch chunk (small: keep VGPRs < 128, no spill)

typedef _Float16 f16;
typedef _Float16 f16x8 __attribute__((ext_vector_type(8)));
typedef _Float16 f16x4 __attribute__((ext_vector_type(4)));
typedef float    f32x4 __attribute__((ext_vector_type(4)));

__device__ __forceinline__ void async_copy16(const void* g, void* l) {
    __builtin_amdgcn_global_load_lds((const __attribute__((address_space(1))) void*)g,
                                     (__attribute__((address_space(3))) void*)l,
                                     16, 0, 0);
}

// ---- fp32 -> f16 conversion of x -------------------------------------------
__global__ __launch_bounds__(256) void conv_x_kernel(const float* __restrict__ x,
                                                     f16* __restrict__ xh) {
    const size_t i = (size_t)blockIdx.x * 256 + threadIdx.x;
    const f32x4 v = *(const f32x4*)(x + 4*i);
    f16x4 h; h.x = (f16)v.x; h.y = (f16)v.y; h.z = (f16)v.z; h.w = (f16)v.w;
    *(f16x4*)(xh + 4*i) = h;
}

// ---- fp32 -> f16 of [W_state; W_gate] as one [2048,1024] row-major matrix --
__global__ __launch_bounds__(256) void conv_w_kernel(const float* __restrict__ Ws,
                                                     const float* __restrict__ Wg,
                                                     f16* __restrict__ wc) {
    const int i = blockIdx.x * 256 + threadIdx.x;
    const int e = i * 4;
    const int n = e >> 10;
    const int k = e & 1023;
    const float* src = (n < DC) ? (Ws + (size_t)n * DC + k)
                                : (Wg + (size_t)(n - DC) * DC + k);
    const f32x4 v = *(const f32x4*)src;
    f16x4 h; h.x = (f16)v.x; h.y = (f16)v.y; h.z = (f16)v.z; h.w = (f16)v.w;
    *(f16x4*)(wc + e) = h;
}

// ---- fused GEMM: [32768,1024] x [2048,1024]^T, bias + (sigmoid for gate) ---
// 128x128 tile, BK=64, 4 waves, each 64x64 via 4x4 grid of 16x16x32 f16 MFMAs.
// LDS uses an XOR-8 chunk swizzle: logical (row, chunk c) lives at physical
// chunk c^(row&7). Staging picks the swizzled GLOBAL source per lane (the
// lane->LDS mapping of global_load_lds is fixed); fragment reads XOR on the
// LDS side. Result: each ds_read_b128 spreads over all 32 banks (8/bank =
// structural floor), killing the 5e7 conflict cycles of the unswizzled form.
__global__ __launch_bounds__(256, 4) void gemm_kernel(
        const f16* __restrict__ xh, const f16* __restrict__ wc,
        const float* __restrict__ b_state, const float* __restrict__ b_gate,
        f16* __restrict__ pxh, f16* __restrict__ gh) {
    __shared__ f16 lds_a[128 * 64];
    __shared__ f16 lds_b[128 * 64];

    const int tid  = threadIdx.x;
    const int lane = tid & 63;
    // XCD-aware remap: blocks land on XCD (blockIdx.x & 7) [heuristic].
    // Give each XCD a 32-row slab of bm with bn fastest: B (4 MB) stays
    // resident in that XCD's L2; each A tile is read by exactly one XCD.
    const int xcd = blockIdx.x & 7;
    const int lin = blockIdx.x >> 3;       // 0..511
    const int bm  = xcd * 32 + (lin >> 4); // 0..255
    const int bn  = lin & 15;              // 0..15
    const int wave = tid >> 6;
    const int wm   = (wave & 1) * 64;
    const int wn   = (wave >> 1) * 64;
    const int lr   = lane & 15;
    const int lq   = lane >> 4;

    f32x4 acc[4][4] = {};

    const int kc = tid & 7;                // dest 16B chunk within 64-half row
    const int rw = tid >> 3;               // dest row (within 32-row stripe)
    const int kg = kc ^ (rw & 7);          // swizzled global source chunk
    const int ldsbase = (tid & 192) * 16;  // wave-uniform byte base
    const int sw = lr & 7;                 // read-side swizzle key (row&7)

    for (int kt = 0; kt < GK / 64; ++kt) {
        const int k0 = kt * 64;
        #pragma unroll
        for (int i = 0; i < 4; ++i) {
            const int row = i * 32 + rw;
            async_copy16(xh + (size_t)(bm * 128 + row) * GK + k0 + kg * 8,
                         (char*)lds_a + ldsbase + i * 4096);
            async_copy16(wc + (size_t)(bn * 128 + row) * GK + k0 + kg * 8,
                         (char*)lds_b + ldsbase + i * 4096);
        }
        __syncthreads();
        #pragma unroll
        for (int ks = 0; ks < 2; ++ks) {
            f16x8 af[4], bf[4];
            #pragma unroll
            for (int t = 0; t < 4; ++t) {
                const int pc = (ks * 4 + lq) ^ sw;   // physical chunk
                af[t] = *(const f16x8*)&lds_a[(wm + t * 16 + lr) * 64 + pc * 8];
                bf[t] = *(const f16x8*)&lds_b[(wn + t * 16 + lr) * 64 + pc * 8];
            }
            #pragma unroll
            for (int im = 0; im < 4; ++im)
                #pragma unroll
                for (int in = 0; in < 4; ++in)
                    acc[im][in] = __builtin_amdgcn_mfma_f32_16x16x32_f16(
                        af[im], bf[in], acc[im][in], 0, 0, 0);
        }
        __syncthreads();
    }

    // Epilogue. D layout: col = lane&15, row = quad*4 + reg (verified m89).
    const int gm0 = bm * 128 + wm + lq * 4;
    const int gn0 = bn * 128 + wn + lr;
    if (bn < 8) {
        #pragma unroll
        for (int in = 0; in < 4; ++in) {
            const int gn = gn0 + in * 16;
            const float bias = b_state[gn];
            #pragma unroll
            for (int im = 0; im < 4; ++im) {
                const int gm = gm0 + im * 16;
                #pragma unroll
                for (int r = 0; r < 4; ++r)
                    pxh[(size_t)(gm + r) * DC + gn] = (f16)(acc[im][in][r] + bias);
            }
        }
    } else {
        #pragma unroll
        for (int in = 0; in < 4; ++in) {
            const int gn   = gn0 + in * 16;
            const int gcol = gn - DC;
            const float bias = b_gate[gcol];
            #pragma unroll
            for (int im = 0; im < 4; ++im) {
                const int gm = gm0 + im * 16;
                #pragma unroll
                for (int r = 0; r < 4; ++r) {
                    const float v = acc[im][in][r] + bias;
                    gh[(size_t)(gm + r) * DC + gcol] = (f16)(1.0f / (1.0f + __expf(-v)));
                }
            }
        }
    }
}

// ---- segmented scan over T: s = tanh(p_t + s); out = g_t * s ---------------
// 8192 chains x 64 segments of 64 steps; each segment (except first) warms up
// 64 steps from s=0 (error decays by prod(1-tanh^2) ~ e^-38 typical).
// tanh(z) = 1 - 2/(1+2^(L*z)), L = 2*log2(e); track sL = L*s so the dependent
// chain is fma->exp2->add->rcp->fma. UCH=8 keeps live registers ~70 (< 128
// cap at 4 waves/EU): round-1's 315us was scratch spill from U=32 arrays.
__global__ __launch_bounds__(256, 4) void scan_kernel(
        const f16* __restrict__ ph, const f16* __restrict__ gh,
        float* __restrict__ out) {
    const int tau   = blockIdx.x * 256 + threadIdx.x;   // 0..524287
    const int seg   = tau >> 13;                        // 0..63 (wave-uniform)
    const int chain = tau & 8191;
    const size_t base = (size_t)(chain >> 10) * ((size_t)DT * DC) + (chain & 1023);
    const float L = 2.8853900817779268f;                // 2*log2(e)
    float sL = 0.0f, s = 0.0f;
    const int t0 = seg * SEG;

    if (seg) {  // warmup: p only, no g, no stores
        const int tw = t0 - WU;
        f16 wA[UCH], wB[UCH];
        #pragma unroll
        for (int i = 0; i < UCH; ++i) wA[i] = ph[base + (size_t)(tw + i) * DC];
        #pragma unroll 1
        for (int ch = 0; ch < WU / UCH; ++ch) {
            #pragma unroll
            for (int i = 0; i < UCH; ++i)   // last iter reads t0..t0+7: valid
                wB[i] = ph[base + (size_t)(tw + (ch + 1) * UCH + i) * DC];
            #pragma unroll
            for (int i = 0; i < UCH; ++i) {
                const float u = fmaf((float)wA[i], L, sL);
                const float e = __builtin_amdgcn_exp2f(u);
                const float r = __builtin_amdgcn_rcpf(e + 1.0f);
                sL = fmaf(-2.0f * L, r, L);
            }
            #pragma unroll
            for (int i = 0; i < UCH; ++i) wA[i] = wB[i];
        }
    }

    float pA[UCH], pB[UCH], gA[UCH], gB[UCH];
    #pragma unroll
    for (int i = 0; i < UCH; ++i) {
        const size_t idx = base + (size_t)(t0 + i) * DC;
        pA[i] = (float)ph[idx] * L;
        gA[i] = (float)gh[idx];
    }
    #pragma unroll 1
    for (int ch = 0; ch < SEG / UCH; ++ch) {
        // Unconditional next-chunk prefetch (ph/gh padded by 16 steps, so
        // segment 63's final prefetch at t=4096..4103 stays in bounds).
        #pragma unroll
        for (int i = 0; i < UCH; ++i) {
            const size_t idx = base + (size_t)(t0 + (ch + 1) * UCH + i) * DC;
            pB[i] = (float)ph[idx] * L;
            gB[i] = (float)gh[idx];
        }
        #pragma unroll
        for (int i = 0; i < UCH; ++i) {
            const float u = pA[i] + sL;
            const float e = __builtin_amdgcn_exp2f(u);
            const float r = __builtin_amdgcn_rcpf(e + 1.0f);
            s  = fmaf(-2.0f, r, 1.0f);
            sL = fmaf(-2.0f * L, r, L);
            out[base + (size_t)(t0 + ch * UCH + i) * DC] = gA[i] * s;
        }
        #pragma unroll
        for (int i = 0; i < UCH; ++i) { pA[i] = pB[i]; gA[i] = gB[i]; }
    }
    if (seg == NSEG - 1) out[(size_t)DB * DT * DC + chain] = s;  // final_state
}

extern "C" void kernel_launch(void* const* d_in, const int* in_sizes, int n_in,
                              void* d_out, int out_size, void* d_ws, size_t ws_size,
                              hipStream_t stream) {
    const float* x  = (const float*)d_in[0];
    const float* Ws = (const float*)d_in[1];
    const float* bs = (const float*)d_in[2];
    const float* Wg = (const float*)d_in[3];
    const float* bg = (const float*)d_in[4];
    float* out = (float*)d_out;

    // workspace layout (~196 MiB; round-2 WRITE_SIZE confirms ws is ample):
    //   xh  f16[32768][1024], wc f16[2048][1024],
    //   pxh f16[32768+16][1024], gh f16[32768+16][1024]
    char* ws = (char*)d_ws;
    const size_t SZ_XH  = (size_t)GM * GK * 2;
    const size_t SZ_WC  = (size_t)GN * GK * 2;
    const size_t SZ_PXH = ((size_t)GM + 16) * DC * 2;
    f16* xh  = (f16*)ws;
    f16* wc  = (f16*)(ws + SZ_XH);
    f16* pxh = (f16*)(ws + SZ_XH + SZ_WC);
    f16* gh  = (f16*)(ws + SZ_XH + SZ_WC + SZ_PXH);

    conv_x_kernel<<<dim3(GM * GK / 1024), dim3(256), 0, stream>>>(x, xh);
    conv_w_kernel<<<dim3(GN * GK / 1024), dim3(256), 0, stream>>>(Ws, Wg, wc);
    gemm_kernel<<<dim3(4096), dim3(256), 0, stream>>>(xh, wc, bs, bg, pxh, gh);
    scan_kernel<<<dim3(DB * DC * NSEG / 256), dim3(256), 0, stream>>>(pxh, gh, out);
}